// Round 1
// baseline (556.053 us; speedup 1.0000x reference)
//
#include <hip/hip_runtime.h>
#include <hip/hip_bf16.h>
#include <math.h>

#define N_NODES 50000
#define DIM 128
#define HID 64
#define SLOPE 0.2f

// ---------------------------------------------------------------------------
// GEMM: C[M,N] = act(A[M,K] @ W[K,N] + b[N]),  act = relu if relu!=0
// BM=64, BN=64, BK=16; 256 threads (16x16), each thread computes 4x4.
// ---------------------------------------------------------------------------
__global__ __launch_bounds__(256) void gemm_bias_act(
    const float* __restrict__ A, const float* __restrict__ W,
    const float* __restrict__ b, float* __restrict__ C,
    int M, int K, int N, int relu)
{
    __shared__ float As[16][64 + 4];  // As[k][m]
    __shared__ float Bs[16][64 + 4];  // Bs[k][n]
    const int tid = threadIdx.x;
    const int tx = tid & 15, ty = tid >> 4;
    const int m0 = blockIdx.x * 64;
    const int n0 = blockIdx.y * 64;

    float acc[4][4] = {};

    for (int k0 = 0; k0 < K; k0 += 16) {
        // A tile: 64 rows x 16 k (row-major A, stride K)
        {
            int m  = tid >> 2;         // 0..63
            int k4 = (tid & 3) * 4;    // 0,4,8,12
            float4 v = make_float4(0.f, 0.f, 0.f, 0.f);
            int row = m0 + m;
            if (row < M)
                v = *reinterpret_cast<const float4*>(&A[(size_t)row * K + k0 + k4]);
            As[k4 + 0][m] = v.x; As[k4 + 1][m] = v.y;
            As[k4 + 2][m] = v.z; As[k4 + 3][m] = v.w;
        }
        // B tile: 16 k x 64 n (row-major W, stride N)
        {
            int k  = tid >> 4;         // 0..15
            int n4 = (tid & 15) * 4;   // 0..60
            float4 v = *reinterpret_cast<const float4*>(&W[(size_t)(k0 + k) * N + n0 + n4]);
            Bs[k][n4 + 0] = v.x; Bs[k][n4 + 1] = v.y;
            Bs[k][n4 + 2] = v.z; Bs[k][n4 + 3] = v.w;
        }
        __syncthreads();
        #pragma unroll
        for (int k = 0; k < 16; k++) {
            float a[4], bb[4];
            #pragma unroll
            for (int i = 0; i < 4; i++) a[i]  = As[k][ty * 4 + i];
            #pragma unroll
            for (int j = 0; j < 4; j++) bb[j] = Bs[k][tx * 4 + j];
            #pragma unroll
            for (int i = 0; i < 4; i++)
                #pragma unroll
                for (int j = 0; j < 4; j++)
                    acc[i][j] = fmaf(a[i], bb[j], acc[i][j]);
        }
        __syncthreads();
    }

    #pragma unroll
    for (int i = 0; i < 4; i++) {
        int row = m0 + ty * 4 + i;
        if (row >= M) continue;
        #pragma unroll
        for (int j = 0; j < 4; j++) {
            int col = n0 + tx * 4 + j;
            float v = acc[i][j] + b[col];
            if (relu) v = fmaxf(v, 0.f);
            C[(size_t)row * N + col] = v;
        }
    }
}

// ---------------------------------------------------------------------------
// CSR build: count -> scan -> fill
// ---------------------------------------------------------------------------
__global__ __launch_bounds__(256) void count_kernel(
    const int* __restrict__ dst, int E, int* __restrict__ counts)
{
    int e = blockIdx.x * blockDim.x + threadIdx.x;
    if (e < E) atomicAdd(&counts[dst[e]], 1);
}

__global__ __launch_bounds__(1024) void scan_kernel(
    const int* __restrict__ counts, int* __restrict__ offsets, int n)
{
    __shared__ int part[1024];
    const int t = threadIdx.x;
    const int chunk = (n + 1023) / 1024;
    const int lo = t * chunk;
    const int hi = min(n, lo + chunk);
    int s = 0;
    for (int i = lo; i < hi; i++) s += counts[i];
    part[t] = s;
    __syncthreads();
    for (int d = 1; d < 1024; d <<= 1) {
        int v = (t >= d) ? part[t - d] : 0;
        __syncthreads();
        part[t] += v;
        __syncthreads();
    }
    int run = (t == 0) ? 0 : part[t - 1];
    for (int i = lo; i < hi; i++) { offsets[i] = run; run += counts[i]; }
}

__global__ __launch_bounds__(256) void fill_kernel(
    const int* __restrict__ src, const int* __restrict__ dst, int E,
    const int* __restrict__ offsets, int* __restrict__ cursor,
    int* __restrict__ src_sorted)
{
    int e = blockIdx.x * blockDim.x + threadIdx.x;
    if (e >= E) return;
    int d = dst[e];
    int pos = offsets[d] + atomicAdd(&cursor[d], 1);
    src_sorted[pos] = src[e];
}

// ---------------------------------------------------------------------------
// GATv2 aggregate: one 32-lane group per destination node.
// Online softmax over incoming edges; each lane owns 4 of the 128 dims.
// ---------------------------------------------------------------------------
__global__ __launch_bounds__(256) void gat_aggregate(
    const float* __restrict__ xl, const float* __restrict__ xr,
    const int* __restrict__ offsets, const int* __restrict__ counts,
    const int* __restrict__ src_sorted,
    const float* __restrict__ att, const float* __restrict__ bias,
    float* __restrict__ out, int n_dst)
{
    const int g    = (blockIdx.x * blockDim.x + threadIdx.x) >> 5;
    const int lane = threadIdx.x & 31;
    if (g >= n_dst) return;

    const float4 xr4  = *reinterpret_cast<const float4*>(&xr[(size_t)g * DIM + lane * 4]);
    const float4 att4 = *reinterpret_cast<const float4*>(&att[lane * 4]);
    const int start = offsets[g];
    const int deg   = counts[g];

    float m = -INFINITY, s = 0.f;
    float4 acc = make_float4(0.f, 0.f, 0.f, 0.f);

    for (int i = 0; i < deg; i++) {
        int srcn = src_sorted[start + i];
        float4 a = *reinterpret_cast<const float4*>(&xl[(size_t)srcn * DIM + lane * 4]);
        float zx = a.x + xr4.x, zy = a.y + xr4.y, zz = a.z + xr4.z, zw = a.w + xr4.w;
        zx = (zx > 0.f) ? zx : SLOPE * zx;
        zy = (zy > 0.f) ? zy : SLOPE * zy;
        zz = (zz > 0.f) ? zz : SLOPE * zz;
        zw = (zw > 0.f) ? zw : SLOPE * zw;
        float p = att4.x * zx + att4.y * zy + att4.z * zz + att4.w * zw;
        #pragma unroll
        for (int o = 16; o; o >>= 1) p += __shfl_xor(p, o, 32);
        const float logit = p;                 // identical on all 32 lanes
        if (logit > m) {                       // online-softmax rescale
            float scale = __expf(m - logit);   // 0 on first edge (m=-inf)
            s *= scale;
            acc.x *= scale; acc.y *= scale; acc.z *= scale; acc.w *= scale;
            m = logit;
        }
        float w = __expf(logit - m);
        s += w;
        acc.x = fmaf(w, a.x, acc.x);
        acc.y = fmaf(w, a.y, acc.y);
        acc.z = fmaf(w, a.z, acc.z);
        acc.w = fmaf(w, a.w, acc.w);
    }

    const float inv = 1.f / (s + 1e-16f);      // deg==0 -> acc==0 -> out = bias
    const float4 b4 = *reinterpret_cast<const float4*>(&bias[lane * 4]);
    float4 o4;
    o4.x = acc.x * inv + b4.x;
    o4.y = acc.y * inv + b4.y;
    o4.z = acc.z * inv + b4.z;
    o4.w = acc.w * inv + b4.w;
    *reinterpret_cast<float4*>(&out[(size_t)g * DIM + lane * 4]) = o4;
}

// ---------------------------------------------------------------------------
// Host-side driver
// ---------------------------------------------------------------------------
static void run_relation(
    const float* hsrc, const float* Wl, const float* bl,
    const float* hdst, const float* Wr, const float* br,
    const int* edge, int E, const float* att, const float* bias,
    float* out, float* XL, float* XR,
    int* counts, int* offsets, int* cursor, int* src_sorted,
    hipStream_t stream)
{
    dim3 blk(256);
    dim3 gp((N_NODES + 63) / 64, DIM / 64);
    gemm_bias_act<<<gp, blk, 0, stream>>>(hsrc, Wl, bl, XL, N_NODES, DIM, DIM, 0);
    gemm_bias_act<<<gp, blk, 0, stream>>>(hdst, Wr, br, XR, N_NODES, DIM, DIM, 0);

    hipMemsetAsync(counts, 0, N_NODES * sizeof(int), stream);
    hipMemsetAsync(cursor, 0, N_NODES * sizeof(int), stream);

    const int* src = edge;
    const int* dst = edge + E;
    count_kernel<<<(E + 255) / 256, blk, 0, stream>>>(dst, E, counts);
    scan_kernel<<<1, 1024, 0, stream>>>(counts, offsets, N_NODES);
    fill_kernel<<<(E + 255) / 256, blk, 0, stream>>>(src, dst, E, offsets, cursor, src_sorted);

    int ng = (N_NODES * 32 + 255) / 256;
    gat_aggregate<<<ng, blk, 0, stream>>>(XL, XR, offsets, counts, src_sorted,
                                          att, bias, out, N_NODES);
}

extern "C" void kernel_launch(void* const* d_in, const int* in_sizes, int n_in,
                              void* d_out, int out_size, void* d_ws, size_t ws_size,
                              hipStream_t stream)
{
    const float* x_user   = (const float*)d_in[0];
    const float* x_item   = (const float*)d_in[1];
    const int*   edge_u2i = (const int*)d_in[2];
    const int*   edge_i2u = (const int*)d_in[3];
    const float* W1_user  = (const float*)d_in[4];
    const float* b1_user  = (const float*)d_in[5];
    const float* W2_user  = (const float*)d_in[6];
    const float* b2_user  = (const float*)d_in[7];
    const float* W1_item  = (const float*)d_in[8];
    const float* b1_item  = (const float*)d_in[9];
    const float* W2_item  = (const float*)d_in[10];
    const float* b2_item  = (const float*)d_in[11];
    const float* Wl_u2i   = (const float*)d_in[12];
    const float* bl_u2i   = (const float*)d_in[13];
    const float* Wr_u2i   = (const float*)d_in[14];
    const float* br_u2i   = (const float*)d_in[15];
    const float* att_u2i  = (const float*)d_in[16];
    const float* bias_u2i = (const float*)d_in[17];
    const float* Wl_i2u   = (const float*)d_in[18];
    const float* bl_i2u   = (const float*)d_in[19];
    const float* Wr_i2u   = (const float*)d_in[20];
    const float* br_i2u   = (const float*)d_in[21];
    const float* att_i2u  = (const float*)d_in[22];
    const float* bias_i2u = (const float*)d_in[23];

    const int E1 = in_sizes[2] / 2;
    const int E2 = in_sizes[3] / 2;

    const size_t NF = (size_t)N_NODES * DIM;   // 6.4M floats
    float* ws = (float*)d_ws;
    float* HU = ws;
    float* HI = HU + NF;
    float* XL = HI + NF;                       // also MLP-hidden scratch
    float* XR = XL + NF;
    int* ibase      = (int*)(XR + NF);
    int* counts     = ibase;
    int* offsets    = counts + N_NODES;
    int* cursor     = offsets + N_NODES;
    int* src_sorted = cursor + N_NODES;

    float* out_user = (float*)d_out;
    float* out_item = out_user + NF;

    dim3 blk(256);
    dim3 g1((N_NODES + 63) / 64, HID / 64);    // [N,128]@[128,64]
    dim3 g2((N_NODES + 63) / 64, DIM / 64);    // [N,64]@[64,128]

    // MLPs (hidden staged in XL, free at this point)
    gemm_bias_act<<<g1, blk, 0, stream>>>(x_user, W1_user, b1_user, XL, N_NODES, DIM, HID, 1);
    gemm_bias_act<<<g2, blk, 0, stream>>>(XL, W2_user, b2_user, HU, N_NODES, HID, DIM, 0);
    gemm_bias_act<<<g1, blk, 0, stream>>>(x_item, W1_item, b1_item, XL, N_NODES, DIM, HID, 1);
    gemm_bias_act<<<g2, blk, 0, stream>>>(XL, W2_item, b2_item, HI, N_NODES, HID, DIM, 0);

    // u2i: src=user(HU,Wl), dst=item(HI,Wr) -> out_item
    run_relation(HU, Wl_u2i, bl_u2i, HI, Wr_u2i, br_u2i, edge_u2i, E1,
                 att_u2i, bias_u2i, out_item, XL, XR,
                 counts, offsets, cursor, src_sorted, stream);
    // i2u: src=item(HI,Wl), dst=user(HU,Wr) -> out_user
    run_relation(HI, Wl_i2u, bl_i2u, HU, Wr_i2u, br_i2u, edge_i2u, E2,
                 att_i2u, bias_i2u, out_user, XL, XR,
                 counts, offsets, cursor, src_sorted, stream);
}

// Round 2
// 423.330 us; speedup vs baseline: 1.3135x; 1.3135x over previous
//
#include <hip/hip_runtime.h>
#include <hip/hip_bf16.h>
#include <math.h>

#define N_NODES 50000
#define DIM 128
#define HID 64
#define SLOPE 0.2f

// ---------------------------------------------------------------------------
// GEMM: C[M,N] = act(A[M,K] @ W[K,N] + b[N]),  act = relu if relu!=0
// BM=64, BN=64, BK=16; 256 threads (16x16), each thread computes 4x4.
// ---------------------------------------------------------------------------
__global__ __launch_bounds__(256) void gemm_bias_act(
    const float* __restrict__ A, const float* __restrict__ W,
    const float* __restrict__ b, float* __restrict__ C,
    int M, int K, int N, int relu)
{
    __shared__ float As[16][64 + 4];  // As[k][m]
    __shared__ float Bs[16][64 + 4];  // Bs[k][n]
    const int tid = threadIdx.x;
    const int tx = tid & 15, ty = tid >> 4;
    const int m0 = blockIdx.x * 64;
    const int n0 = blockIdx.y * 64;

    float acc[4][4] = {};

    for (int k0 = 0; k0 < K; k0 += 16) {
        {
            int m  = tid >> 2;         // 0..63
            int k4 = (tid & 3) * 4;    // 0,4,8,12
            float4 v = make_float4(0.f, 0.f, 0.f, 0.f);
            int row = m0 + m;
            if (row < M)
                v = *reinterpret_cast<const float4*>(&A[(size_t)row * K + k0 + k4]);
            As[k4 + 0][m] = v.x; As[k4 + 1][m] = v.y;
            As[k4 + 2][m] = v.z; As[k4 + 3][m] = v.w;
        }
        {
            int k  = tid >> 4;         // 0..15
            int n4 = (tid & 15) * 4;   // 0..60
            float4 v = *reinterpret_cast<const float4*>(&W[(size_t)(k0 + k) * N + n0 + n4]);
            Bs[k][n4 + 0] = v.x; Bs[k][n4 + 1] = v.y;
            Bs[k][n4 + 2] = v.z; Bs[k][n4 + 3] = v.w;
        }
        __syncthreads();
        #pragma unroll
        for (int k = 0; k < 16; k++) {
            float a[4], bb[4];
            #pragma unroll
            for (int i = 0; i < 4; i++) a[i]  = As[k][ty * 4 + i];
            #pragma unroll
            for (int j = 0; j < 4; j++) bb[j] = Bs[k][tx * 4 + j];
            #pragma unroll
            for (int i = 0; i < 4; i++)
                #pragma unroll
                for (int j = 0; j < 4; j++)
                    acc[i][j] = fmaf(a[i], bb[j], acc[i][j]);
        }
        __syncthreads();
    }

    #pragma unroll
    for (int i = 0; i < 4; i++) {
        int row = m0 + ty * 4 + i;
        if (row >= M) continue;
        #pragma unroll
        for (int j = 0; j < 4; j++) {
            int col = n0 + tx * 4 + j;
            float v = acc[i][j] + b[col];
            if (relu) v = fmaxf(v, 0.f);
            C[(size_t)row * N + col] = v;
        }
    }
}

// ---------------------------------------------------------------------------
// CSR build: count -> hierarchical scan (3 kernels) -> fill
// ---------------------------------------------------------------------------
__global__ __launch_bounds__(256) void count_kernel(
    const int* __restrict__ dst, int E, int* __restrict__ counts)
{
    int e = blockIdx.x * blockDim.x + threadIdx.x;
    if (e < E) atomicAdd(&counts[dst[e]], 1);
}

// A: per-block (256-wide) sum of counts -> bsums[block]
__global__ __launch_bounds__(256) void scan_partial(
    const int* __restrict__ counts, int* __restrict__ bsums, int n)
{
    __shared__ int sm[256];
    int i = blockIdx.x * 256 + threadIdx.x;
    sm[threadIdx.x] = (i < n) ? counts[i] : 0;
    __syncthreads();
    #pragma unroll
    for (int d = 128; d; d >>= 1) {
        if (threadIdx.x < d) sm[threadIdx.x] += sm[threadIdx.x + d];
        __syncthreads();
    }
    if (threadIdx.x == 0) bsums[blockIdx.x] = sm[0];
}

// B: exclusive scan of bsums in-place (nb <= 1024), single block
__global__ __launch_bounds__(1024) void scan_bsums(int* __restrict__ bsums, int nb)
{
    __shared__ int sm[1024];
    const int t = threadIdx.x;
    const int v = (t < nb) ? bsums[t] : 0;
    sm[t] = v;
    __syncthreads();
    for (int d = 1; d < 1024; d <<= 1) {
        int x = (t >= d) ? sm[t - d] : 0;
        __syncthreads();
        sm[t] += x;
        __syncthreads();
    }
    if (t < nb) bsums[t] = sm[t] - v;   // exclusive
}

// C: offsets[i] = bsums[block] + exclusive-scan-within-block(counts)
__global__ __launch_bounds__(256) void scan_final(
    const int* __restrict__ counts, const int* __restrict__ bsums,
    int* __restrict__ offsets, int n)
{
    __shared__ int sm[256];
    int i = blockIdx.x * 256 + threadIdx.x;
    const int v = (i < n) ? counts[i] : 0;
    sm[threadIdx.x] = v;
    __syncthreads();
    #pragma unroll
    for (int d = 1; d < 256; d <<= 1) {
        int x = (threadIdx.x >= d) ? sm[threadIdx.x - d] : 0;
        __syncthreads();
        sm[threadIdx.x] += x;
        __syncthreads();
    }
    if (i < n) offsets[i] = bsums[blockIdx.x] + sm[threadIdx.x] - v;
}

__global__ __launch_bounds__(256) void fill_kernel(
    const int* __restrict__ src, const int* __restrict__ dst, int E,
    const int* __restrict__ offsets, int* __restrict__ cursor,
    int* __restrict__ src_sorted)
{
    int e = blockIdx.x * blockDim.x + threadIdx.x;
    if (e >= E) return;
    int d = dst[e];
    int pos = offsets[d] + atomicAdd(&cursor[d], 1);
    src_sorted[pos] = src[e];
}

// ---------------------------------------------------------------------------
// GATv2 aggregate: one 32-lane group per destination node.
// Online softmax over incoming edges; each lane owns 4 of the 128 dims.
// ---------------------------------------------------------------------------
__global__ __launch_bounds__(256) void gat_aggregate(
    const float* __restrict__ xl, const float* __restrict__ xr,
    const int* __restrict__ offsets, const int* __restrict__ counts,
    const int* __restrict__ src_sorted,
    const float* __restrict__ att, const float* __restrict__ bias,
    float* __restrict__ out, int n_dst)
{
    const int g    = (blockIdx.x * blockDim.x + threadIdx.x) >> 5;
    const int lane = threadIdx.x & 31;
    if (g >= n_dst) return;

    const float4 xr4  = *reinterpret_cast<const float4*>(&xr[(size_t)g * DIM + lane * 4]);
    const float4 att4 = *reinterpret_cast<const float4*>(&att[lane * 4]);
    const int start = offsets[g];
    const int deg   = counts[g];

    float m = -INFINITY, s = 0.f;
    float4 acc = make_float4(0.f, 0.f, 0.f, 0.f);

    for (int i = 0; i < deg; i++) {
        int srcn = src_sorted[start + i];
        float4 a = *reinterpret_cast<const float4*>(&xl[(size_t)srcn * DIM + lane * 4]);
        float zx = a.x + xr4.x, zy = a.y + xr4.y, zz = a.z + xr4.z, zw = a.w + xr4.w;
        zx = (zx > 0.f) ? zx : SLOPE * zx;
        zy = (zy > 0.f) ? zy : SLOPE * zy;
        zz = (zz > 0.f) ? zz : SLOPE * zz;
        zw = (zw > 0.f) ? zw : SLOPE * zw;
        float p = att4.x * zx + att4.y * zy + att4.z * zz + att4.w * zw;
        #pragma unroll
        for (int o = 16; o; o >>= 1) p += __shfl_xor(p, o, 32);
        const float logit = p;                 // identical on all 32 lanes
        if (logit > m) {                       // online-softmax rescale
            float scale = __expf(m - logit);   // 0 on first edge (m=-inf)
            s *= scale;
            acc.x *= scale; acc.y *= scale; acc.z *= scale; acc.w *= scale;
            m = logit;
        }
        float w = __expf(logit - m);
        s += w;
        acc.x = fmaf(w, a.x, acc.x);
        acc.y = fmaf(w, a.y, acc.y);
        acc.z = fmaf(w, a.z, acc.z);
        acc.w = fmaf(w, a.w, acc.w);
    }

    const float inv = 1.f / (s + 1e-16f);      // deg==0 -> acc==0 -> out = bias
    const float4 b4 = *reinterpret_cast<const float4*>(&bias[lane * 4]);
    float4 o4;
    o4.x = acc.x * inv + b4.x;
    o4.y = acc.y * inv + b4.y;
    o4.z = acc.z * inv + b4.z;
    o4.w = acc.w * inv + b4.w;
    *reinterpret_cast<float4*>(&out[(size_t)g * DIM + lane * 4]) = o4;
}

// ---------------------------------------------------------------------------
// Host-side driver
// ---------------------------------------------------------------------------
static void run_relation(
    const float* hsrc, const float* Wl, const float* bl,
    const float* hdst, const float* Wr, const float* br,
    const int* edge, int E, const float* att, const float* bias,
    float* out, float* XL, float* XR,
    int* counts, int* offsets, int* cursor, int* src_sorted, int* bsums,
    hipStream_t stream)
{
    dim3 blk(256);
    dim3 gp((N_NODES + 63) / 64, DIM / 64);
    gemm_bias_act<<<gp, blk, 0, stream>>>(hsrc, Wl, bl, XL, N_NODES, DIM, DIM, 0);
    gemm_bias_act<<<gp, blk, 0, stream>>>(hdst, Wr, br, XR, N_NODES, DIM, DIM, 0);

    hipMemsetAsync(counts, 0, N_NODES * sizeof(int), stream);
    hipMemsetAsync(cursor, 0, N_NODES * sizeof(int), stream);

    const int* src = edge;
    const int* dst = edge + E;
    const int nb = (N_NODES + 255) / 256;      // 196
    count_kernel<<<(E + 255) / 256, blk, 0, stream>>>(dst, E, counts);
    scan_partial<<<nb, blk, 0, stream>>>(counts, bsums, N_NODES);
    scan_bsums<<<1, 1024, 0, stream>>>(bsums, nb);
    scan_final<<<nb, blk, 0, stream>>>(counts, bsums, offsets, N_NODES);
    fill_kernel<<<(E + 255) / 256, blk, 0, stream>>>(src, dst, E, offsets, cursor, src_sorted);

    int ng = (N_NODES * 32 + 255) / 256;
    gat_aggregate<<<ng, blk, 0, stream>>>(XL, XR, offsets, counts, src_sorted,
                                          att, bias, out, N_NODES);
}

extern "C" void kernel_launch(void* const* d_in, const int* in_sizes, int n_in,
                              void* d_out, int out_size, void* d_ws, size_t ws_size,
                              hipStream_t stream)
{
    const float* x_user   = (const float*)d_in[0];
    const float* x_item   = (const float*)d_in[1];
    const int*   edge_u2i = (const int*)d_in[2];
    const int*   edge_i2u = (const int*)d_in[3];
    const float* W1_user  = (const float*)d_in[4];
    const float* b1_user  = (const float*)d_in[5];
    const float* W2_user  = (const float*)d_in[6];
    const float* b2_user  = (const float*)d_in[7];
    const float* W1_item  = (const float*)d_in[8];
    const float* b1_item  = (const float*)d_in[9];
    const float* W2_item  = (const float*)d_in[10];
    const float* b2_item  = (const float*)d_in[11];
    const float* Wl_u2i   = (const float*)d_in[12];
    const float* bl_u2i   = (const float*)d_in[13];
    const float* Wr_u2i   = (const float*)d_in[14];
    const float* br_u2i   = (const float*)d_in[15];
    const float* att_u2i  = (const float*)d_in[16];
    const float* bias_u2i = (const float*)d_in[17];
    const float* Wl_i2u   = (const float*)d_in[18];
    const float* bl_i2u   = (const float*)d_in[19];
    const float* Wr_i2u   = (const float*)d_in[20];
    const float* br_i2u   = (const float*)d_in[21];
    const float* att_i2u  = (const float*)d_in[22];
    const float* bias_i2u = (const float*)d_in[23];

    const int E1 = in_sizes[2] / 2;
    const int E2 = in_sizes[3] / 2;

    const size_t NF = (size_t)N_NODES * DIM;   // 6.4M floats
    float* ws = (float*)d_ws;
    float* HU = ws;
    float* HI = HU + NF;
    float* XL = HI + NF;                       // also MLP-hidden scratch
    float* XR = XL + NF;
    int* ibase      = (int*)(XR + NF);
    int* counts     = ibase;
    int* offsets    = counts + N_NODES;
    int* cursor     = offsets + N_NODES;
    int* bsums      = cursor + N_NODES;
    int* src_sorted = bsums + 1024;

    float* out_user = (float*)d_out;
    float* out_item = out_user + NF;

    dim3 blk(256);
    dim3 g1((N_NODES + 63) / 64, HID / 64);    // [N,128]@[128,64]
    dim3 g2((N_NODES + 63) / 64, DIM / 64);    // [N,64]@[64,128]

    // MLPs (hidden staged in XL, free at this point)
    gemm_bias_act<<<g1, blk, 0, stream>>>(x_user, W1_user, b1_user, XL, N_NODES, DIM, HID, 1);
    gemm_bias_act<<<g2, blk, 0, stream>>>(XL, W2_user, b2_user, HU, N_NODES, HID, DIM, 0);
    gemm_bias_act<<<g1, blk, 0, stream>>>(x_item, W1_item, b1_item, XL, N_NODES, DIM, HID, 1);
    gemm_bias_act<<<g2, blk, 0, stream>>>(XL, W2_item, b2_item, HI, N_NODES, HID, DIM, 0);

    // u2i: src=user(HU,Wl), dst=item(HI,Wr) -> out_item
    run_relation(HU, Wl_u2i, bl_u2i, HI, Wr_u2i, br_u2i, edge_u2i, E1,
                 att_u2i, bias_u2i, out_item, XL, XR,
                 counts, offsets, cursor, src_sorted, bsums, stream);
    // i2u: src=item(HI,Wl), dst=user(HU,Wr) -> out_user
    run_relation(HI, Wl_i2u, bl_i2u, HU, Wr_i2u, br_i2u, edge_i2u, E2,
                 att_i2u, bias_i2u, out_user, XL, XR,
                 counts, offsets, cursor, src_sorted, bsums, stream);
}

// Round 3
// 312.117 us; speedup vs baseline: 1.7816x; 1.3563x over previous
//
#include <hip/hip_runtime.h>
#include <hip/hip_bf16.h>
#include <math.h>

#define N_NODES 50000
#define DIM 128
#define HID 64
#define SLOPE 0.2f

typedef __attribute__((ext_vector_type(8))) short bf16x8;   // 8 bf16 = 4 VGPRs
typedef __attribute__((ext_vector_type(4))) float f32x4;

// round-to-nearest-even f32 -> bf16 (as ushort bits)
static __device__ __forceinline__ ushort f2bf(float f) {
    uint u = __float_as_uint(f);
    u += 0x7FFFu + ((u >> 16) & 1u);
    return (ushort)(u >> 16);
}
static __device__ __forceinline__ float bf2f(ushort b) {
    return __uint_as_float(((uint)b) << 16);
}

// ---------------------------------------------------------------------------
// f32 -> bf16 bulk convert (n divisible by 4)
// ---------------------------------------------------------------------------
__global__ __launch_bounds__(256) void f32_to_bf16(
    const float* __restrict__ in, ushort* __restrict__ out, int n)
{
    int i = (blockIdx.x * 256 + threadIdx.x) * 4;
    if (i >= n) return;
    float4 v = *reinterpret_cast<const float4*>(&in[i]);
    ushort4 o;
    o.x = f2bf(v.x); o.y = f2bf(v.y); o.z = f2bf(v.z); o.w = f2bf(v.w);
    *reinterpret_cast<ushort4*>(&out[i]) = o;
}

// ---------------------------------------------------------------------------
// MFMA GEMM: C[M,NN](bf16) = act(A[M,KK](bf16) @ W[KK,NN](f32) + bias)
// 256 thr = 4 waves; block covers 64 rows x NN cols. Full W staged in LDS
// transposed (Wt[n][k], +8 pad). mfma_f32_16x16x32_bf16 per 16x16 tile.
// Fragment layouts: A lane l -> row l&15, k=(l>>4)*8+j (contiguous 16B).
//                   B lane l -> col l&15, k=(l>>4)*8+j (16B from Wt row).
//                   D lane l -> col l&15, row=(l>>4)*4+i   [m89-verified]
// ---------------------------------------------------------------------------
template<int KK, int NN, int RELU>
__global__ __launch_bounds__(256) void gemm_mfma(
    const ushort* __restrict__ A, const float* __restrict__ W,
    const float* __restrict__ bias, ushort* __restrict__ C, int M)
{
    __shared__ ushort Wt[NN][KK + 8];
    const int tid = threadIdx.x;

    // stage W (row-major [KK][NN] f32) -> Wt[n][k] bf16
    for (int idx = tid; idx < KK * NN; idx += 256) {
        int k = idx / NN;
        int n = idx - k * NN;
        Wt[n][k] = f2bf(W[idx]);
    }
    __syncthreads();

    const int wave = tid >> 6;
    const int lane = tid & 63;
    const int half = lane >> 4;        // 0..3
    const int quad = lane & 15;        // 0..15
    const int row  = blockIdx.x * 64 + wave * 16 + quad;
    const int srow = row < M ? row : M - 1;

    f32x4 acc[NN / 16] = {};

    #pragma unroll
    for (int kt = 0; kt < KK / 32; ++kt) {
        bf16x8 a = *reinterpret_cast<const bf16x8*>(
            &A[(size_t)srow * KK + kt * 32 + half * 8]);
        #pragma unroll
        for (int n = 0; n < NN / 16; ++n) {
            bf16x8 b = *reinterpret_cast<const bf16x8*>(
                &Wt[n * 16 + quad][kt * 32 + half * 8]);
            acc[n] = __builtin_amdgcn_mfma_f32_16x16x32_bf16(a, b, acc[n], 0, 0, 0);
        }
    }

    const int orow0 = blockIdx.x * 64 + wave * 16 + half * 4;
    #pragma unroll
    for (int n = 0; n < NN / 16; ++n) {
        const int col = n * 16 + quad;
        const float bv = bias[col];
        #pragma unroll
        for (int i = 0; i < 4; ++i) {
            const int r = orow0 + i;
            if (r < M) {
                float v = acc[n][i] + bv;
                if (RELU) v = fmaxf(v, 0.f);
                C[(size_t)r * NN + col] = f2bf(v);
            }
        }
    }
}

// ---------------------------------------------------------------------------
// CSR build: count -> hierarchical scan -> fill
// ---------------------------------------------------------------------------
__global__ __launch_bounds__(256) void count_kernel(
    const int* __restrict__ dst, int E, int* __restrict__ counts)
{
    int e = blockIdx.x * blockDim.x + threadIdx.x;
    if (e < E) atomicAdd(&counts[dst[e]], 1);
}

__global__ __launch_bounds__(256) void scan_partial(
    const int* __restrict__ counts, int* __restrict__ bsums, int n)
{
    __shared__ int sm[256];
    int i = blockIdx.x * 256 + threadIdx.x;
    sm[threadIdx.x] = (i < n) ? counts[i] : 0;
    __syncthreads();
    #pragma unroll
    for (int d = 128; d; d >>= 1) {
        if (threadIdx.x < d) sm[threadIdx.x] += sm[threadIdx.x + d];
        __syncthreads();
    }
    if (threadIdx.x == 0) bsums[blockIdx.x] = sm[0];
}

__global__ __launch_bounds__(1024) void scan_bsums(int* __restrict__ bsums, int nb)
{
    __shared__ int sm[1024];
    const int t = threadIdx.x;
    const int v = (t < nb) ? bsums[t] : 0;
    sm[t] = v;
    __syncthreads();
    for (int d = 1; d < 1024; d <<= 1) {
        int x = (t >= d) ? sm[t - d] : 0;
        __syncthreads();
        sm[t] += x;
        __syncthreads();
    }
    if (t < nb) bsums[t] = sm[t] - v;   // exclusive
}

__global__ __launch_bounds__(256) void scan_final(
    const int* __restrict__ counts, const int* __restrict__ bsums,
    int* __restrict__ offsets, int n)
{
    __shared__ int sm[256];
    int i = blockIdx.x * 256 + threadIdx.x;
    const int v = (i < n) ? counts[i] : 0;
    sm[threadIdx.x] = v;
    __syncthreads();
    #pragma unroll
    for (int d = 1; d < 256; d <<= 1) {
        int x = (threadIdx.x >= d) ? sm[threadIdx.x - d] : 0;
        __syncthreads();
        sm[threadIdx.x] += x;
        __syncthreads();
    }
    if (i < n) offsets[i] = bsums[blockIdx.x] + sm[threadIdx.x] - v;
}

__global__ __launch_bounds__(256) void fill_kernel(
    const int* __restrict__ src, const int* __restrict__ dst, int E,
    const int* __restrict__ offsets, int* __restrict__ cursor,
    int* __restrict__ src_sorted)
{
    int e = blockIdx.x * blockDim.x + threadIdx.x;
    if (e >= E) return;
    int d = dst[e];
    int pos = offsets[d] + atomicAdd(&cursor[d], 1);
    src_sorted[pos] = src[e];
}

// ---------------------------------------------------------------------------
// GATv2 aggregate: one 32-lane group per destination node, bf16 gather,
// online softmax, unroll-2 (two independent gathers in flight).
// ---------------------------------------------------------------------------
static __device__ __forceinline__ float4 load_bf4(const ushort* p) {
    ushort4 u = *reinterpret_cast<const ushort4*>(p);
    float4 f;
    f.x = bf2f(u.x); f.y = bf2f(u.y); f.z = bf2f(u.z); f.w = bf2f(u.w);
    return f;
}

static __device__ __forceinline__ float edge_partial(
    float4 a, float4 xr4, float4 att4)
{
    float zx = a.x + xr4.x, zy = a.y + xr4.y, zz = a.z + xr4.z, zw = a.w + xr4.w;
    zx = (zx > 0.f) ? zx : SLOPE * zx;
    zy = (zy > 0.f) ? zy : SLOPE * zy;
    zz = (zz > 0.f) ? zz : SLOPE * zz;
    zw = (zw > 0.f) ? zw : SLOPE * zw;
    return att4.x * zx + att4.y * zy + att4.z * zz + att4.w * zw;
}

__global__ __launch_bounds__(256) void gat_aggregate(
    const ushort* __restrict__ xl, const ushort* __restrict__ xr,
    const int* __restrict__ offsets, const int* __restrict__ counts,
    const int* __restrict__ src_sorted,
    const float* __restrict__ att, const float* __restrict__ bias,
    float* __restrict__ out, int n_dst)
{
    const int g    = (blockIdx.x * blockDim.x + threadIdx.x) >> 5;
    const int lane = threadIdx.x & 31;
    if (g >= n_dst) return;

    const float4 xr4  = load_bf4(&xr[(size_t)g * DIM + lane * 4]);
    const float4 att4 = *reinterpret_cast<const float4*>(&att[lane * 4]);
    const int start = offsets[g];
    const int deg   = counts[g];

    float m = -INFINITY, s = 0.f;
    float4 acc = make_float4(0.f, 0.f, 0.f, 0.f);

    int i = 0;
    for (; i + 2 <= deg; i += 2) {
        int s0 = src_sorted[start + i];
        int s1 = src_sorted[start + i + 1];
        float4 a0 = load_bf4(&xl[(size_t)s0 * DIM + lane * 4]);
        float4 a1 = load_bf4(&xl[(size_t)s1 * DIM + lane * 4]);
        float p0 = edge_partial(a0, xr4, att4);
        float p1 = edge_partial(a1, xr4, att4);
        #pragma unroll
        for (int o = 16; o; o >>= 1) {
            p0 += __shfl_xor(p0, o, 32);
            p1 += __shfl_xor(p1, o, 32);
        }
        float mn = fmaxf(p0, p1);
        if (mn > m) {
            float scale = __expf(m - mn);
            s *= scale;
            acc.x *= scale; acc.y *= scale; acc.z *= scale; acc.w *= scale;
            m = mn;
        }
        float w0 = __expf(p0 - m);
        float w1 = __expf(p1 - m);
        s += w0 + w1;
        acc.x += w0 * a0.x + w1 * a1.x;
        acc.y += w0 * a0.y + w1 * a1.y;
        acc.z += w0 * a0.z + w1 * a1.z;
        acc.w += w0 * a0.w + w1 * a1.w;
    }
    if (i < deg) {
        int s0 = src_sorted[start + i];
        float4 a0 = load_bf4(&xl[(size_t)s0 * DIM + lane * 4]);
        float p0 = edge_partial(a0, xr4, att4);
        #pragma unroll
        for (int o = 16; o; o >>= 1) p0 += __shfl_xor(p0, o, 32);
        if (p0 > m) {
            float scale = __expf(m - p0);
            s *= scale;
            acc.x *= scale; acc.y *= scale; acc.z *= scale; acc.w *= scale;
            m = p0;
        }
        float w0 = __expf(p0 - m);
        s += w0;
        acc.x += w0 * a0.x; acc.y += w0 * a0.y;
        acc.z += w0 * a0.z; acc.w += w0 * a0.w;
    }

    const float inv = 1.f / (s + 1e-16f);      // deg==0 -> acc==0 -> out = bias
    const float4 b4 = *reinterpret_cast<const float4*>(&bias[lane * 4]);
    float4 o4;
    o4.x = acc.x * inv + b4.x;
    o4.y = acc.y * inv + b4.y;
    o4.z = acc.z * inv + b4.z;
    o4.w = acc.w * inv + b4.w;
    *reinterpret_cast<float4*>(&out[(size_t)g * DIM + lane * 4]) = o4;
}

// ---------------------------------------------------------------------------
// Host-side driver
// ---------------------------------------------------------------------------
static void run_relation(
    const ushort* XLsrc_h, const float* Wl, const float* bl,
    const ushort* XRdst_h, const float* Wr, const float* br,
    const int* edge, int E, const float* att, const float* bias,
    float* out, ushort* XL, ushort* XR,
    int* counts, int* offsets, int* cursor, int* src_sorted, int* bsums,
    hipStream_t stream)
{
    dim3 blk(256);
    const int gb = (N_NODES + 63) / 64;
    gemm_mfma<128, 128, 0><<<gb, blk, 0, stream>>>(XLsrc_h, Wl, bl, XL, N_NODES);
    gemm_mfma<128, 128, 0><<<gb, blk, 0, stream>>>(XRdst_h, Wr, br, XR, N_NODES);

    hipMemsetAsync(counts, 0, N_NODES * sizeof(int), stream);
    hipMemsetAsync(cursor, 0, N_NODES * sizeof(int), stream);

    const int* src = edge;
    const int* dst = edge + E;
    const int nb = (N_NODES + 255) / 256;      // 196
    count_kernel<<<(E + 255) / 256, blk, 0, stream>>>(dst, E, counts);
    scan_partial<<<nb, blk, 0, stream>>>(counts, bsums, N_NODES);
    scan_bsums<<<1, 1024, 0, stream>>>(bsums, nb);
    scan_final<<<nb, blk, 0, stream>>>(counts, bsums, offsets, N_NODES);
    fill_kernel<<<(E + 255) / 256, blk, 0, stream>>>(src, dst, E, offsets, cursor, src_sorted);

    int ng = (N_NODES * 32 + 255) / 256;
    gat_aggregate<<<ng, blk, 0, stream>>>(XL, XR, offsets, counts, src_sorted,
                                          att, bias, out, N_NODES);
}

extern "C" void kernel_launch(void* const* d_in, const int* in_sizes, int n_in,
                              void* d_out, int out_size, void* d_ws, size_t ws_size,
                              hipStream_t stream)
{
    const float* x_user   = (const float*)d_in[0];
    const float* x_item   = (const float*)d_in[1];
    const int*   edge_u2i = (const int*)d_in[2];
    const int*   edge_i2u = (const int*)d_in[3];
    const float* W1_user  = (const float*)d_in[4];
    const float* b1_user  = (const float*)d_in[5];
    const float* W2_user  = (const float*)d_in[6];
    const float* b2_user  = (const float*)d_in[7];
    const float* W1_item  = (const float*)d_in[8];
    const float* b1_item  = (const float*)d_in[9];
    const float* W2_item  = (const float*)d_in[10];
    const float* b2_item  = (const float*)d_in[11];
    const float* Wl_u2i   = (const float*)d_in[12];
    const float* bl_u2i   = (const float*)d_in[13];
    const float* Wr_u2i   = (const float*)d_in[14];
    const float* br_u2i   = (const float*)d_in[15];
    const float* att_u2i  = (const float*)d_in[16];
    const float* bias_u2i = (const float*)d_in[17];
    const float* Wl_i2u   = (const float*)d_in[18];
    const float* bl_i2u   = (const float*)d_in[19];
    const float* Wr_i2u   = (const float*)d_in[20];
    const float* br_i2u   = (const float*)d_in[21];
    const float* att_i2u  = (const float*)d_in[22];
    const float* bias_i2u = (const float*)d_in[23];

    const int E1 = in_sizes[2] / 2;
    const int E2 = in_sizes[3] / 2;

    const size_t NF = (size_t)N_NODES * DIM;   // 6.4M elems
    ushort* XU = (ushort*)d_ws;
    ushort* XI = XU + NF;
    ushort* HU = XI + NF;
    ushort* HI = HU + NF;
    ushort* HD = HI + NF;                      // hidden [N,64]
    ushort* XL = HD + NF / 2;
    ushort* XR = XL + NF;
    int* ibase      = (int*)(XR + NF);
    int* counts     = ibase;
    int* offsets    = counts + N_NODES;
    int* cursor     = offsets + N_NODES;
    int* bsums      = cursor + N_NODES;
    int* src_sorted = bsums + 1024;

    float* out_user = (float*)d_out;
    float* out_item = out_user + NF;

    dim3 blk(256);
    const int gb = (N_NODES + 63) / 64;
    const int nconv = (int)(NF / 4 + 255) / 256;

    f32_to_bf16<<<nconv, blk, 0, stream>>>(x_user, XU, (int)NF);
    f32_to_bf16<<<nconv, blk, 0, stream>>>(x_item, XI, (int)NF);

    // MLPs
    gemm_mfma<128, 64, 1><<<gb, blk, 0, stream>>>(XU, W1_user, b1_user, HD, N_NODES);
    gemm_mfma<64, 128, 0><<<gb, blk, 0, stream>>>(HD, W2_user, b2_user, HU, N_NODES);
    gemm_mfma<128, 64, 1><<<gb, blk, 0, stream>>>(XI, W1_item, b1_item, HD, N_NODES);
    gemm_mfma<64, 128, 0><<<gb, blk, 0, stream>>>(HD, W2_item, b2_item, HI, N_NODES);

    // u2i: src=user(HU,Wl), dst=item(HI,Wr) -> out_item
    run_relation(HU, Wl_u2i, bl_u2i, HI, Wr_u2i, br_u2i, edge_u2i, E1,
                 att_u2i, bias_u2i, out_item, XL, XR,
                 counts, offsets, cursor, src_sorted, bsums, stream);
    // i2u: src=item(HI,Wl), dst=user(HU,Wr) -> out_user
    run_relation(HI, Wl_i2u, bl_i2u, HU, Wr_i2u, br_i2u, edge_i2u, E2,
                 att_i2u, bias_i2u, out_user, XL, XR,
                 counts, offsets, cursor, src_sorted, bsums, stream);
}

// Round 4
// 237.386 us; speedup vs baseline: 2.3424x; 1.3148x over previous
//
#include <hip/hip_runtime.h>
#include <hip/hip_bf16.h>
#include <math.h>

#define N_NODES 50000
#define DIM 128
#define HID 64
#define SLOPE 0.2f

typedef __attribute__((ext_vector_type(8))) short bf16x8;   // 8 bf16 = 4 VGPRs
typedef __attribute__((ext_vector_type(4))) float f32x4;

// Fragment-ordered weight blob layout (ushort offsets)
#define OW1 0
#define OW2 8192
#define OWL 16384
#define OWR 32768
#define BLOB 49152          // total ushorts = 96 KiB

static __device__ __forceinline__ ushort f2bf(float f) {
    uint u = __float_as_uint(f);
    u += 0x7FFFu + ((u >> 16) & 1u);
    return (ushort)(u >> 16);
}
static __device__ __forceinline__ float bf2f(ushort b) {
    return __uint_as_float(((uint)b) << 16);
}

// ---------------------------------------------------------------------------
// prep_weights: f32 row-major [K][N] -> bf16 MFMA-fragment order.
// frag index = ((n_tile*nkt + kt)*64 + lane)*8 + j
//   holds W[k = kt*32 + (lane>>4)*8 + j][col = n_tile*16 + (lane&15)]
// ---------------------------------------------------------------------------
__global__ __launch_bounds__(256) void prep_weights(
    const float* __restrict__ W1, const float* __restrict__ W2,
    const float* __restrict__ Wl, const float* __restrict__ Wr,
    ushort* __restrict__ blob)
{
    int idx = blockIdx.x * 256 + threadIdx.x;
    if (idx >= BLOB) return;
    const float* W; int NN, nkt, rel;
    if (idx < OW2)      { W = W1; NN = 64;  nkt = 4; rel = idx; }        // K=128,N=64
    else if (idx < OWL) { W = W2; NN = 128; nkt = 2; rel = idx - OW2; }  // K=64, N=128
    else if (idx < OWR) { W = Wl; NN = 128; nkt = 4; rel = idx - OWL; }  // K=128,N=128
    else                { W = Wr; NN = 128; nkt = 4; rel = idx - OWR; }
    int j = rel & 7, l = (rel >> 3) & 63, t = rel >> 9;
    int kt = t % nkt, n = t / nkt;
    int k   = kt * 32 + (l >> 4) * 8 + j;
    int col = n * 16 + (l & 15);
    blob[idx] = f2bf(W[k * NN + col]);
}

// ---------------------------------------------------------------------------
// node_transform: per node type, fully fused dense chain.
//   h  = relu(x@W1 + b1)        [N,64]
//   h2 = h@W2 + b2              [N,128]
//   XL = h2@Wl + bl (bf16)      [N,128]
//   XR = h2@Wr + br (bf16)      [N,128]
// 512 thr = 8 waves, 16 rows/wave, 128 rows/block. Weights in LDS
// (fragment order: B-read = base + lane*16B, conflict-free). h/h2 repack
// via per-wave LDS tile (D-layout write -> A-layout read).
// ---------------------------------------------------------------------------
__global__ __launch_bounds__(512) void node_transform(
    const float* __restrict__ x, const ushort* __restrict__ blob,
    const float* __restrict__ b1, const float* __restrict__ b2,
    const float* __restrict__ bl, const float* __restrict__ br,
    ushort* __restrict__ XL, ushort* __restrict__ XR, int M)
{
    __shared__ ushort lds[BLOB + 8 * 16 * 136];   // 96KB weights + 34KB stage = 130KB
    const int tid = threadIdx.x;

    // stage weight blob (linear 16B copies)
    {
        const uint4* s = (const uint4*)blob;
        uint4* d = (uint4*)lds;
        #pragma unroll
        for (int i = 0; i < 12; ++i)          // 512*12*16B = 98304B = BLOB*2
            d[tid + i * 512] = s[tid + i * 512];
    }
    __syncthreads();

    const int wave = tid >> 6, lane = tid & 63;
    const int quad = lane & 15, half = lane >> 4;
    ushort* hstage = lds + BLOB + wave * (16 * 136);
    const int rbase = blockIdx.x * 128 + wave * 16;
    const int row  = rbase + quad;
    const int srow = row < M ? row : M - 1;

    // A1 frags from x (f32 -> bf16), K=128
    bf16x8 a1[4];
    #pragma unroll
    for (int kt = 0; kt < 4; ++kt) {
        const float* p = &x[(size_t)srow * DIM + kt * 32 + half * 8];
        float4 f0 = *(const float4*)p;
        float4 f1 = *(const float4*)(p + 4);
        bf16x8 a;
        a[0] = (short)f2bf(f0.x); a[1] = (short)f2bf(f0.y);
        a[2] = (short)f2bf(f0.z); a[3] = (short)f2bf(f0.w);
        a[4] = (short)f2bf(f1.x); a[5] = (short)f2bf(f1.y);
        a[6] = (short)f2bf(f1.z); a[7] = (short)f2bf(f1.w);
        a1[kt] = a;
    }

    // h = relu(x@W1 + b1): 4 n-tiles, 4 kt
    f32x4 hacc[4] = {};
    #pragma unroll
    for (int kt = 0; kt < 4; ++kt)
        #pragma unroll
        for (int n = 0; n < 4; ++n) {
            bf16x8 b = *(const bf16x8*)&lds[OW1 + (size_t)((n * 4 + kt) * 64 + lane) * 8];
            hacc[n] = __builtin_amdgcn_mfma_f32_16x16x32_bf16(a1[kt], b, hacc[n], 0, 0, 0);
        }
    #pragma unroll
    for (int n = 0; n < 4; ++n) {
        int col = n * 16 + quad;
        float bv = b1[col];
        #pragma unroll
        for (int i = 0; i < 4; ++i)
            hstage[(half * 4 + i) * 136 + col] = f2bf(fmaxf(hacc[n][i] + bv, 0.f));
    }

    // a2 frags (K=64) — wave-local RAW through LDS, in-order DS pipe + waitcnt
    bf16x8 a2[2];
    #pragma unroll
    for (int kt = 0; kt < 2; ++kt)
        a2[kt] = *(const bf16x8*)&hstage[quad * 136 + kt * 32 + half * 8];

    // h2 = h@W2 + b2: 8 n-tiles, 2 kt
    f32x4 h2acc[8] = {};
    #pragma unroll
    for (int kt = 0; kt < 2; ++kt)
        #pragma unroll
        for (int n = 0; n < 8; ++n) {
            bf16x8 b = *(const bf16x8*)&lds[OW2 + (size_t)((n * 2 + kt) * 64 + lane) * 8];
            h2acc[n] = __builtin_amdgcn_mfma_f32_16x16x32_bf16(a2[kt], b, h2acc[n], 0, 0, 0);
        }
    #pragma unroll
    for (int n = 0; n < 8; ++n) {
        int col = n * 16 + quad;
        float bv = b2[col];
        #pragma unroll
        for (int i = 0; i < 4; ++i)
            hstage[(half * 4 + i) * 136 + col] = f2bf(h2acc[n][i] + bv);
    }

    // a3 frags (K=128)
    bf16x8 a3[4];
    #pragma unroll
    for (int kt = 0; kt < 4; ++kt)
        a3[kt] = *(const bf16x8*)&hstage[quad * 136 + kt * 32 + half * 8];

    // XL = h2@Wl + bl ; XR = h2@Wr + br
    f32x4 accL[8] = {}, accR[8] = {};
    #pragma unroll
    for (int kt = 0; kt < 4; ++kt)
        #pragma unroll
        for (int n = 0; n < 8; ++n) {
            bf16x8 bL = *(const bf16x8*)&lds[OWL + (size_t)((n * 4 + kt) * 64 + lane) * 8];
            accL[n] = __builtin_amdgcn_mfma_f32_16x16x32_bf16(a3[kt], bL, accL[n], 0, 0, 0);
            bf16x8 bR = *(const bf16x8*)&lds[OWR + (size_t)((n * 4 + kt) * 64 + lane) * 8];
            accR[n] = __builtin_amdgcn_mfma_f32_16x16x32_bf16(a3[kt], bR, accR[n], 0, 0, 0);
        }

    #pragma unroll
    for (int n = 0; n < 8; ++n) {
        int col = n * 16 + quad;
        float blv = bl[col];
        float brv = br[col];
        #pragma unroll
        for (int i = 0; i < 4; ++i) {
            int r = rbase + half * 4 + i;
            if (r < M) {
                XL[(size_t)r * DIM + col] = f2bf(accL[n][i] + blv);
                XR[(size_t)r * DIM + col] = f2bf(accR[n][i] + brv);
            }
        }
    }
}

// ---------------------------------------------------------------------------
// Batched CSR build for both relations: count -> 3-stage scan over 2N -> fill
// counts2 layout: [0..N) = u2i dsts (items), [N..2N) = i2u dsts (users)
// ---------------------------------------------------------------------------
__global__ __launch_bounds__(256) void count_both(
    const int* __restrict__ e1, int E1, const int* __restrict__ e2, int E2,
    int* __restrict__ counts2)
{
    int e = blockIdx.x * 256 + threadIdx.x;
    if (e < E1) {
        atomicAdd(&counts2[e1[E1 + e]], 1);
    } else if (e < E1 + E2) {
        int i = e - E1;
        atomicAdd(&counts2[N_NODES + e2[E2 + i]], 1);
    }
}

__global__ __launch_bounds__(256) void scan_partial(
    const int* __restrict__ counts, int* __restrict__ bsums, int n)
{
    __shared__ int sm[256];
    int i = blockIdx.x * 256 + threadIdx.x;
    sm[threadIdx.x] = (i < n) ? counts[i] : 0;
    __syncthreads();
    #pragma unroll
    for (int d = 128; d; d >>= 1) {
        if (threadIdx.x < d) sm[threadIdx.x] += sm[threadIdx.x + d];
        __syncthreads();
    }
    if (threadIdx.x == 0) bsums[blockIdx.x] = sm[0];
}

__global__ __launch_bounds__(1024) void scan_bsums(int* __restrict__ bsums, int nb)
{
    __shared__ int sm[1024];
    const int t = threadIdx.x;
    const int v = (t < nb) ? bsums[t] : 0;
    sm[t] = v;
    __syncthreads();
    for (int d = 1; d < 1024; d <<= 1) {
        int x = (t >= d) ? sm[t - d] : 0;
        __syncthreads();
        sm[t] += x;
        __syncthreads();
    }
    if (t < nb) bsums[t] = sm[t] - v;   // exclusive
}

__global__ __launch_bounds__(256) void scan_final(
    const int* __restrict__ counts, const int* __restrict__ bsums,
    int* __restrict__ offsets, int n)
{
    __shared__ int sm[256];
    int i = blockIdx.x * 256 + threadIdx.x;
    const int v = (i < n) ? counts[i] : 0;
    sm[threadIdx.x] = v;
    __syncthreads();
    #pragma unroll
    for (int d = 1; d < 256; d <<= 1) {
        int x = (threadIdx.x >= d) ? sm[threadIdx.x - d] : 0;
        __syncthreads();
        sm[threadIdx.x] += x;
        __syncthreads();
    }
    if (i < n) offsets[i] = bsums[blockIdx.x] + sm[threadIdx.x] - v;
}

__global__ __launch_bounds__(256) void fill_both(
    const int* __restrict__ e1, int E1, const int* __restrict__ e2, int E2,
    const int* __restrict__ offsets2, int* __restrict__ cursor2,
    int* __restrict__ src_sorted)
{
    int e = blockIdx.x * 256 + threadIdx.x;
    int s, di;
    if (e < E1) {
        s = e1[e]; di = e1[E1 + e];
    } else if (e < E1 + E2) {
        int i = e - E1;
        s = e2[i]; di = N_NODES + e2[E2 + i];
    } else return;
    int pos = offsets2[di] + atomicAdd(&cursor2[di], 1);
    src_sorted[pos] = s;
}

// ---------------------------------------------------------------------------
// GATv2 aggregate: one 32-lane group per destination node, bf16 gather,
// online softmax, unroll-2.
// ---------------------------------------------------------------------------
static __device__ __forceinline__ float4 load_bf4(const ushort* p) {
    ushort4 u = *reinterpret_cast<const ushort4*>(p);
    float4 f;
    f.x = bf2f(u.x); f.y = bf2f(u.y); f.z = bf2f(u.z); f.w = bf2f(u.w);
    return f;
}

static __device__ __forceinline__ float edge_partial(
    float4 a, float4 xr4, float4 att4)
{
    float zx = a.x + xr4.x, zy = a.y + xr4.y, zz = a.z + xr4.z, zw = a.w + xr4.w;
    zx = (zx > 0.f) ? zx : SLOPE * zx;
    zy = (zy > 0.f) ? zy : SLOPE * zy;
    zz = (zz > 0.f) ? zz : SLOPE * zz;
    zw = (zw > 0.f) ? zw : SLOPE * zw;
    return att4.x * zx + att4.y * zy + att4.z * zz + att4.w * zw;
}

__global__ __launch_bounds__(256) void gat_aggregate(
    const ushort* __restrict__ xl, const ushort* __restrict__ xr,
    const int* __restrict__ offsets, const int* __restrict__ counts,
    const int* __restrict__ src_sorted,
    const float* __restrict__ att, const float* __restrict__ bias,
    float* __restrict__ out, int n_dst)
{
    const int g    = (blockIdx.x * blockDim.x + threadIdx.x) >> 5;
    const int lane = threadIdx.x & 31;
    if (g >= n_dst) return;

    const float4 xr4  = load_bf4(&xr[(size_t)g * DIM + lane * 4]);
    const float4 att4 = *reinterpret_cast<const float4*>(&att[lane * 4]);
    const int start = offsets[g];
    const int deg   = counts[g];

    float m = -INFINITY, s = 0.f;
    float4 acc = make_float4(0.f, 0.f, 0.f, 0.f);

    int i = 0;
    for (; i + 2 <= deg; i += 2) {
        int s0 = src_sorted[start + i];
        int s1 = src_sorted[start + i + 1];
        float4 a0 = load_bf4(&xl[(size_t)s0 * DIM + lane * 4]);
        float4 a1 = load_bf4(&xl[(size_t)s1 * DIM + lane * 4]);
        float p0 = edge_partial(a0, xr4, att4);
        float p1 = edge_partial(a1, xr4, att4);
        #pragma unroll
        for (int o = 16; o; o >>= 1) {
            p0 += __shfl_xor(p0, o, 32);
            p1 += __shfl_xor(p1, o, 32);
        }
        float mn = fmaxf(p0, p1);
        if (mn > m) {
            float scale = __expf(m - mn);
            s *= scale;
            acc.x *= scale; acc.y *= scale; acc.z *= scale; acc.w *= scale;
            m = mn;
        }
        float w0 = __expf(p0 - m);
        float w1 = __expf(p1 - m);
        s += w0 + w1;
        acc.x += w0 * a0.x + w1 * a1.x;
        acc.y += w0 * a0.y + w1 * a1.y;
        acc.z += w0 * a0.z + w1 * a1.z;
        acc.w += w0 * a0.w + w1 * a1.w;
    }
    if (i < deg) {
        int s0 = src_sorted[start + i];
        float4 a0 = load_bf4(&xl[(size_t)s0 * DIM + lane * 4]);
        float p0 = edge_partial(a0, xr4, att4);
        #pragma unroll
        for (int o = 16; o; o >>= 1) p0 += __shfl_xor(p0, o, 32);
        if (p0 > m) {
            float scale = __expf(m - p0);
            s *= scale;
            acc.x *= scale; acc.y *= scale; acc.z *= scale; acc.w *= scale;
            m = p0;
        }
        float w0 = __expf(p0 - m);
        s += w0;
        acc.x += w0 * a0.x; acc.y += w0 * a0.y;
        acc.z += w0 * a0.z; acc.w += w0 * a0.w;
    }

    const float inv = 1.f / (s + 1e-16f);      // deg==0 -> acc==0 -> out = bias
    const float4 b4 = *reinterpret_cast<const float4*>(&bias[lane * 4]);
    float4 o4;
    o4.x = acc.x * inv + b4.x;
    o4.y = acc.y * inv + b4.y;
    o4.z = acc.z * inv + b4.z;
    o4.w = acc.w * inv + b4.w;
    *reinterpret_cast<float4*>(&out[(size_t)g * DIM + lane * 4]) = o4;
}

// ---------------------------------------------------------------------------
// Host-side driver
// ---------------------------------------------------------------------------
extern "C" void kernel_launch(void* const* d_in, const int* in_sizes, int n_in,
                              void* d_out, int out_size, void* d_ws, size_t ws_size,
                              hipStream_t stream)
{
    const float* x_user   = (const float*)d_in[0];
    const float* x_item   = (const float*)d_in[1];
    const int*   edge_u2i = (const int*)d_in[2];
    const int*   edge_i2u = (const int*)d_in[3];
    const float* W1_user  = (const float*)d_in[4];
    const float* b1_user  = (const float*)d_in[5];
    const float* W2_user  = (const float*)d_in[6];
    const float* b2_user  = (const float*)d_in[7];
    const float* W1_item  = (const float*)d_in[8];
    const float* b1_item  = (const float*)d_in[9];
    const float* W2_item  = (const float*)d_in[10];
    const float* b2_item  = (const float*)d_in[11];
    const float* Wl_u2i   = (const float*)d_in[12];
    const float* bl_u2i   = (const float*)d_in[13];
    const float* Wr_u2i   = (const float*)d_in[14];
    const float* br_u2i   = (const float*)d_in[15];
    const float* att_u2i  = (const float*)d_in[16];
    const float* bias_u2i = (const float*)d_in[17];
    const float* Wl_i2u   = (const float*)d_in[18];
    const float* bl_i2u   = (const float*)d_in[19];
    const float* Wr_i2u   = (const float*)d_in[20];
    const float* br_i2u   = (const float*)d_in[21];
    const float* att_i2u  = (const float*)d_in[22];
    const float* bias_i2u = (const float*)d_in[23];

    const int E1 = in_sizes[2] / 2;
    const int E2 = in_sizes[3] / 2;

    const size_t NF = (size_t)N_NODES * DIM;
    ushort* XLu = (ushort*)d_ws;        // user as src (u2i)
    ushort* XRu = XLu + NF;             // user as dst (i2u)
    ushort* XLi = XRu + NF;             // item as src (i2u)
    ushort* XRi = XLi + NF;             // item as dst (u2i)
    ushort* blobU = XRi + NF;
    ushort* blobI = blobU + BLOB;
    int* counts2    = (int*)(blobI + BLOB);       // [2N]
    int* cursor2    = counts2 + 2 * N_NODES;      // [2N] (contiguous with counts2)
    int* offsets2   = cursor2 + 2 * N_NODES;      // [2N]
    int* bsums      = offsets2 + 2 * N_NODES;     // [1024]
    int* src_sorted = bsums + 1024;               // [E1+E2]

    float* out_user = (float*)d_out;
    float* out_item = out_user + NF;

    dim3 blk(256);

    // weight prep (fragment-ordered bf16 blobs)
    prep_weights<<<(BLOB + 255) / 256, blk, 0, stream>>>(
        W1_user, W2_user, Wl_u2i, Wr_i2u, blobU);
    prep_weights<<<(BLOB + 255) / 256, blk, 0, stream>>>(
        W1_item, W2_item, Wl_i2u, Wr_u2i, blobI);

    // CSR build (independent of dense phase)
    hipMemsetAsync(counts2, 0, 4 * N_NODES * sizeof(int), stream);  // counts2+cursor2
    const int Etot = E1 + E2;
    count_both<<<(Etot + 255) / 256, blk, 0, stream>>>(edge_u2i, E1, edge_i2u, E2, counts2);
    const int n2 = 2 * N_NODES;
    const int nb = (n2 + 255) / 256;    // 391
    scan_partial<<<nb, blk, 0, stream>>>(counts2, bsums, n2);
    scan_bsums<<<1, 1024, 0, stream>>>(bsums, nb);
    scan_final<<<nb, blk, 0, stream>>>(counts2, bsums, offsets2, n2);
    fill_both<<<(Etot + 255) / 256, blk, 0, stream>>>(
        edge_u2i, E1, edge_i2u, E2, offsets2, cursor2, src_sorted);

    // fused dense chain per node type
    const int gnt = (N_NODES + 127) / 128;   // 391
    node_transform<<<gnt, dim3(512), 0, stream>>>(
        x_user, blobU, b1_user, b2_user, bl_u2i, br_i2u, XLu, XRu, N_NODES);
    node_transform<<<gnt, dim3(512), 0, stream>>>(
        x_item, blobI, b1_item, b2_item, bl_i2u, br_u2i, XLi, XRi, N_NODES);

    // aggregation
    const int ng = (N_NODES * 32 + 255) / 256;
    // u2i: dst=item -> out_item ; xl=XLu, xr=XRi ; offsets in [0,N)
    gat_aggregate<<<ng, blk, 0, stream>>>(XLu, XRi, offsets2, counts2,
                                          src_sorted, att_u2i, bias_u2i,
                                          out_item, N_NODES);
    // i2u: dst=user -> out_user ; xl=XLi, xr=XRu ; offsets in [N,2N)
    gat_aggregate<<<ng, blk, 0, stream>>>(XLi, XRu, offsets2 + N_NODES,
                                          counts2 + N_NODES,
                                          src_sorted, att_i2u, bias_i2u,
                                          out_user, N_NODES);
}

// Round 5
// 222.084 us; speedup vs baseline: 2.5038x; 1.0689x over previous
//
#include <hip/hip_runtime.h>
#include <hip/hip_bf16.h>
#include <math.h>

#define N_NODES 50000
#define DIM 128
#define HID 64
#define SLOPE 0.2f

typedef __attribute__((ext_vector_type(8))) short bf16x8;   // 8 bf16 = 4 VGPRs
typedef __attribute__((ext_vector_type(4))) float f32x4;

// Fragment-ordered weight blob layout (ushort offsets)
#define OW1 0
#define OW2 8192
#define OWL 16384
#define OWR 32768
#define BLOB 49152          // total ushorts = 96 KiB

static __device__ __forceinline__ ushort f2bf(float f) {
    uint u = __float_as_uint(f);
    u += 0x7FFFu + ((u >> 16) & 1u);
    return (ushort)(u >> 16);
}
static __device__ __forceinline__ float bf2f(ushort b) {
    return __uint_as_float(((uint)b) << 16);
}

// ---------------------------------------------------------------------------
// prep_weights: f32 row-major [K][N] -> bf16 MFMA-fragment order.
// frag index = ((n_tile*nkt + kt)*64 + lane)*8 + j
//   holds W[k = kt*32 + (lane>>4)*8 + j][col = n_tile*16 + (lane&15)]
// ---------------------------------------------------------------------------
__global__ __launch_bounds__(256) void prep_weights(
    const float* __restrict__ W1, const float* __restrict__ W2,
    const float* __restrict__ Wl, const float* __restrict__ Wr,
    ushort* __restrict__ blob)
{
    int idx = blockIdx.x * 256 + threadIdx.x;
    if (idx >= BLOB) return;
    const float* W; int NN, nkt, rel;
    if (idx < OW2)      { W = W1; NN = 64;  nkt = 4; rel = idx; }        // K=128,N=64
    else if (idx < OWL) { W = W2; NN = 128; nkt = 2; rel = idx - OW2; }  // K=64, N=128
    else if (idx < OWR) { W = Wl; NN = 128; nkt = 4; rel = idx - OWL; }  // K=128,N=128
    else                { W = Wr; NN = 128; nkt = 4; rel = idx - OWR; }
    int j = rel & 7, l = (rel >> 3) & 63, t = rel >> 9;
    int kt = t % nkt, n = t / nkt;
    int k   = kt * 32 + (l >> 4) * 8 + j;
    int col = n * 16 + (l & 15);
    blob[idx] = f2bf(W[k * NN + col]);
}

// ---------------------------------------------------------------------------
// node_transform: fused dense chain, BOTH node types in one dispatch
// (blockIdx < gnt -> type A, else type B).
//   h  = relu(x@W1 + b1); h2 = h@W2 + b2; XL = h2@Wl + bl; XR = h2@Wr + br
// 512 thr = 8 waves, 16 rows/wave, 128 rows/block. Weights in LDS
// (fragment order: B-read = base + lane*16B, conflict-free). h/h2 repack
// via per-wave LDS tile (D-layout write -> A-layout read).
// ---------------------------------------------------------------------------
__global__ __launch_bounds__(512) void node_transform(
    const float* __restrict__ xA, const ushort* __restrict__ blobA,
    const float* __restrict__ b1A, const float* __restrict__ b2A,
    const float* __restrict__ blA, const float* __restrict__ brA,
    ushort* __restrict__ XLA, ushort* __restrict__ XRA,
    const float* __restrict__ xB, const ushort* __restrict__ blobB,
    const float* __restrict__ b1B, const float* __restrict__ b2B,
    const float* __restrict__ blB, const float* __restrict__ brB,
    ushort* __restrict__ XLB, ushort* __restrict__ XRB,
    int gnt, int M)
{
    __shared__ ushort lds[BLOB + 8 * 16 * 136];   // 96KB weights + 34KB stage
    const int tid = threadIdx.x;

    int bid = blockIdx.x;
    const float *x, *b1, *b2, *bl, *br;
    const ushort* blob;
    ushort *XL, *XR;
    if (bid < gnt) {
        x = xA; blob = blobA; b1 = b1A; b2 = b2A; bl = blA; br = brA;
        XL = XLA; XR = XRA;
    } else {
        bid -= gnt;
        x = xB; blob = blobB; b1 = b1B; b2 = b2B; bl = blB; br = brB;
        XL = XLB; XR = XRB;
    }

    // stage weight blob (linear 16B copies)
    {
        const uint4* s = (const uint4*)blob;
        uint4* d = (uint4*)lds;
        #pragma unroll
        for (int i = 0; i < 12; ++i)          // 512*12*16B = 98304B = BLOB*2
            d[tid + i * 512] = s[tid + i * 512];
    }
    __syncthreads();

    const int wave = tid >> 6, lane = tid & 63;
    const int quad = lane & 15, half = lane >> 4;
    ushort* hstage = lds + BLOB + wave * (16 * 136);
    const int rbase = bid * 128 + wave * 16;
    const int row  = rbase + quad;
    const int srow = row < M ? row : M - 1;

    // A1 frags from x (f32 -> bf16), K=128
    bf16x8 a1[4];
    #pragma unroll
    for (int kt = 0; kt < 4; ++kt) {
        const float* p = &x[(size_t)srow * DIM + kt * 32 + half * 8];
        float4 f0 = *(const float4*)p;
        float4 f1 = *(const float4*)(p + 4);
        bf16x8 a;
        a[0] = (short)f2bf(f0.x); a[1] = (short)f2bf(f0.y);
        a[2] = (short)f2bf(f0.z); a[3] = (short)f2bf(f0.w);
        a[4] = (short)f2bf(f1.x); a[5] = (short)f2bf(f1.y);
        a[6] = (short)f2bf(f1.z); a[7] = (short)f2bf(f1.w);
        a1[kt] = a;
    }

    // h = relu(x@W1 + b1): 4 n-tiles, 4 kt
    f32x4 hacc[4] = {};
    #pragma unroll
    for (int kt = 0; kt < 4; ++kt)
        #pragma unroll
        for (int n = 0; n < 4; ++n) {
            bf16x8 b = *(const bf16x8*)&lds[OW1 + (size_t)((n * 4 + kt) * 64 + lane) * 8];
            hacc[n] = __builtin_amdgcn_mfma_f32_16x16x32_bf16(a1[kt], b, hacc[n], 0, 0, 0);
        }
    #pragma unroll
    for (int n = 0; n < 4; ++n) {
        int col = n * 16 + quad;
        float bv = b1[col];
        #pragma unroll
        for (int i = 0; i < 4; ++i)
            hstage[(half * 4 + i) * 136 + col] = f2bf(fmaxf(hacc[n][i] + bv, 0.f));
    }

    // a2 frags (K=64) — wave-local RAW through LDS (in-order DS pipe)
    bf16x8 a2[2];
    #pragma unroll
    for (int kt = 0; kt < 2; ++kt)
        a2[kt] = *(const bf16x8*)&hstage[quad * 136 + kt * 32 + half * 8];

    // h2 = h@W2 + b2: 8 n-tiles, 2 kt
    f32x4 h2acc[8] = {};
    #pragma unroll
    for (int kt = 0; kt < 2; ++kt)
        #pragma unroll
        for (int n = 0; n < 8; ++n) {
            bf16x8 b = *(const bf16x8*)&lds[OW2 + (size_t)((n * 2 + kt) * 64 + lane) * 8];
            h2acc[n] = __builtin_amdgcn_mfma_f32_16x16x32_bf16(a2[kt], b, h2acc[n], 0, 0, 0);
        }
    #pragma unroll
    for (int n = 0; n < 8; ++n) {
        int col = n * 16 + quad;
        float bv = b2[col];
        #pragma unroll
        for (int i = 0; i < 4; ++i)
            hstage[(half * 4 + i) * 136 + col] = f2bf(h2acc[n][i] + bv);
    }

    // a3 frags (K=128)
    bf16x8 a3[4];
    #pragma unroll
    for (int kt = 0; kt < 4; ++kt)
        a3[kt] = *(const bf16x8*)&hstage[quad * 136 + kt * 32 + half * 8];

    // XL = h2@Wl + bl ; XR = h2@Wr + br
    f32x4 accL[8] = {}, accR[8] = {};
    #pragma unroll
    for (int kt = 0; kt < 4; ++kt)
        #pragma unroll
        for (int n = 0; n < 8; ++n) {
            bf16x8 bL = *(const bf16x8*)&lds[OWL + (size_t)((n * 4 + kt) * 64 + lane) * 8];
            accL[n] = __builtin_amdgcn_mfma_f32_16x16x32_bf16(a3[kt], bL, accL[n], 0, 0, 0);
            bf16x8 bR = *(const bf16x8*)&lds[OWR + (size_t)((n * 4 + kt) * 64 + lane) * 8];
            accR[n] = __builtin_amdgcn_mfma_f32_16x16x32_bf16(a3[kt], bR, accR[n], 0, 0, 0);
        }

    #pragma unroll
    for (int n = 0; n < 8; ++n) {
        int col = n * 16 + quad;
        float blv = bl[col];
        float brv = br[col];
        #pragma unroll
        for (int i = 0; i < 4; ++i) {
            int r = rbase + half * 4 + i;
            if (r < M) {
                XL[(size_t)r * DIM + col] = f2bf(accL[n][i] + blv);
                XR[(size_t)r * DIM + col] = f2bf(accR[n][i] + brv);
            }
        }
    }
}

// ---------------------------------------------------------------------------
// Batched CSR build, ILP-8: count -> 3-stage scan over 2N -> fill
// counts2 layout: [0..N) = u2i dsts (items), [N..2N) = i2u dsts (users)
// ---------------------------------------------------------------------------
__global__ __launch_bounds__(256) void count_both(
    const int* __restrict__ e1, int E1, const int* __restrict__ e2, int E2,
    int* __restrict__ counts2)
{
    const int t = blockIdx.x * 256 + threadIdx.x;
    const int n1 = (E1 + 7) >> 3;
    const int n2 = (E2 + 7) >> 3;
    const int* dp; int base, E, off;
    if (t < n1)           { dp = e1 + E1; base = t * 8;        E = E1; off = 0; }
    else if (t < n1 + n2) { dp = e2 + E2; base = (t - n1) * 8; E = E2; off = N_NODES; }
    else return;
    if (base + 8 <= E && ((E & 3) == 0)) {
        int4 a = *(const int4*)&dp[base];
        int4 b = *(const int4*)&dp[base + 4];
        atomicAdd(&counts2[off + a.x], 1); atomicAdd(&counts2[off + a.y], 1);
        atomicAdd(&counts2[off + a.z], 1); atomicAdd(&counts2[off + a.w], 1);
        atomicAdd(&counts2[off + b.x], 1); atomicAdd(&counts2[off + b.y], 1);
        atomicAdd(&counts2[off + b.z], 1); atomicAdd(&counts2[off + b.w], 1);
    } else {
        int hi = min(E, base + 8);
        for (int k = base; k < hi; ++k) atomicAdd(&counts2[off + dp[k]], 1);
    }
}

__global__ __launch_bounds__(256) void scan_partial(
    const int* __restrict__ counts, int* __restrict__ bsums, int n)
{
    __shared__ int sm[256];
    int i = blockIdx.x * 256 + threadIdx.x;
    sm[threadIdx.x] = (i < n) ? counts[i] : 0;
    __syncthreads();
    #pragma unroll
    for (int d = 128; d; d >>= 1) {
        if (threadIdx.x < d) sm[threadIdx.x] += sm[threadIdx.x + d];
        __syncthreads();
    }
    if (threadIdx.x == 0) bsums[blockIdx.x] = sm[0];
}

__global__ __launch_bounds__(1024) void scan_bsums(int* __restrict__ bsums, int nb)
{
    __shared__ int sm[1024];
    const int t = threadIdx.x;
    const int v = (t < nb) ? bsums[t] : 0;
    sm[t] = v;
    __syncthreads();
    for (int d = 1; d < 1024; d <<= 1) {
        int x = (t >= d) ? sm[t - d] : 0;
        __syncthreads();
        sm[t] += x;
        __syncthreads();
    }
    if (t < nb) bsums[t] = sm[t] - v;   // exclusive
}

__global__ __launch_bounds__(256) void scan_final(
    const int* __restrict__ counts, const int* __restrict__ bsums,
    int* __restrict__ offsets, int n)
{
    __shared__ int sm[256];
    int i = blockIdx.x * 256 + threadIdx.x;
    const int v = (i < n) ? counts[i] : 0;
    sm[threadIdx.x] = v;
    __syncthreads();
    #pragma unroll
    for (int d = 1; d < 256; d <<= 1) {
        int x = (threadIdx.x >= d) ? sm[threadIdx.x - d] : 0;
        __syncthreads();
        sm[threadIdx.x] += x;
        __syncthreads();
    }
    if (i < n) offsets[i] = bsums[blockIdx.x] + sm[threadIdx.x] - v;
}

__global__ __launch_bounds__(256) void fill_both(
    const int* __restrict__ e1, int E1, const int* __restrict__ e2, int E2,
    const int* __restrict__ offsets2, int* __restrict__ cursor2,
    int* __restrict__ src_sorted)
{
    const int t = blockIdx.x * 256 + threadIdx.x;
    const int n1 = (E1 + 7) >> 3;
    const int n2 = (E2 + 7) >> 3;
    const int *sp, *dp; int base, E, off;
    if (t < n1)           { sp = e1; dp = e1 + E1; base = t * 8;        E = E1; off = 0; }
    else if (t < n1 + n2) { sp = e2; dp = e2 + E2; base = (t - n1) * 8; E = E2; off = N_NODES; }
    else return;
    if (base + 8 <= E && ((E & 3) == 0)) {
        int4 s0 = *(const int4*)&sp[base];
        int4 s1 = *(const int4*)&sp[base + 4];
        int4 d0 = *(const int4*)&dp[base];
        int4 d1 = *(const int4*)&dp[base + 4];
        int di, pos;
        di = off + d0.x; pos = offsets2[di] + atomicAdd(&cursor2[di], 1); src_sorted[pos] = s0.x;
        di = off + d0.y; pos = offsets2[di] + atomicAdd(&cursor2[di], 1); src_sorted[pos] = s0.y;
        di = off + d0.z; pos = offsets2[di] + atomicAdd(&cursor2[di], 1); src_sorted[pos] = s0.z;
        di = off + d0.w; pos = offsets2[di] + atomicAdd(&cursor2[di], 1); src_sorted[pos] = s0.w;
        di = off + d1.x; pos = offsets2[di] + atomicAdd(&cursor2[di], 1); src_sorted[pos] = s1.x;
        di = off + d1.y; pos = offsets2[di] + atomicAdd(&cursor2[di], 1); src_sorted[pos] = s1.y;
        di = off + d1.z; pos = offsets2[di] + atomicAdd(&cursor2[di], 1); src_sorted[pos] = s1.z;
        di = off + d1.w; pos = offsets2[di] + atomicAdd(&cursor2[di], 1); src_sorted[pos] = s1.w;
    } else {
        int hi = min(E, base + 8);
        for (int k = base; k < hi; ++k) {
            int di = off + dp[k];
            int pos = offsets2[di] + atomicAdd(&cursor2[di], 1);
            src_sorted[pos] = sp[k];
        }
    }
}

// ---------------------------------------------------------------------------
// GATv2 aggregate, BOTH relations in one dispatch: one 32-lane group per
// destination (g in [0,2N)). bf16 gather, online softmax, unroll-2.
// ---------------------------------------------------------------------------
static __device__ __forceinline__ float4 load_bf4(const ushort* p) {
    ushort4 u = *reinterpret_cast<const ushort4*>(p);
    float4 f;
    f.x = bf2f(u.x); f.y = bf2f(u.y); f.z = bf2f(u.z); f.w = bf2f(u.w);
    return f;
}

static __device__ __forceinline__ float edge_partial(
    float4 a, float4 xr4, float4 att4)
{
    float zx = a.x + xr4.x, zy = a.y + xr4.y, zz = a.z + xr4.z, zw = a.w + xr4.w;
    zx = (zx > 0.f) ? zx : SLOPE * zx;
    zy = (zy > 0.f) ? zy : SLOPE * zy;
    zz = (zz > 0.f) ? zz : SLOPE * zz;
    zw = (zw > 0.f) ? zw : SLOPE * zw;
    return att4.x * zx + att4.y * zy + att4.z * zz + att4.w * zw;
}

__global__ __launch_bounds__(256) void gat_both(
    const ushort* __restrict__ xlA, const ushort* __restrict__ xrA,
    const float* __restrict__ attA, const float* __restrict__ biasA,
    float* __restrict__ outA,
    const ushort* __restrict__ xlB, const ushort* __restrict__ xrB,
    const float* __restrict__ attB, const float* __restrict__ biasB,
    float* __restrict__ outB,
    const int* __restrict__ offsets2, const int* __restrict__ counts2,
    const int* __restrict__ src_sorted)
{
    const int g    = (blockIdx.x * blockDim.x + threadIdx.x) >> 5;
    const int lane = threadIdx.x & 31;
    if (g >= 2 * N_NODES) return;

    const ushort *xl, *xr; const float *att, *bias; float* out; int gl;
    if (g < N_NODES) { xl = xlA; xr = xrA; att = attA; bias = biasA; out = outA; gl = g; }
    else { xl = xlB; xr = xrB; att = attB; bias = biasB; out = outB; gl = g - N_NODES; }

    const float4 xr4  = load_bf4(&xr[(size_t)gl * DIM + lane * 4]);
    const float4 att4 = *reinterpret_cast<const float4*>(&att[lane * 4]);
    const int start = offsets2[g];
    const int deg   = counts2[g];

    float m = -INFINITY, s = 0.f;
    float4 acc = make_float4(0.f, 0.f, 0.f, 0.f);

    int i = 0;
    for (; i + 2 <= deg; i += 2) {
        int s0 = src_sorted[start + i];
        int s1 = src_sorted[start + i + 1];
        float4 a0 = load_bf4(&xl[(size_t)s0 * DIM + lane * 4]);
        float4 a1 = load_bf4(&xl[(size_t)s1 * DIM + lane * 4]);
        float p0 = edge_partial(a0, xr4, att4);
        float p1 = edge_partial(a1, xr4, att4);
        #pragma unroll
        for (int o = 16; o; o >>= 1) {
            p0 += __shfl_xor(p0, o, 32);
            p1 += __shfl_xor(p1, o, 32);
        }
        float mn = fmaxf(p0, p1);
        if (mn > m) {
            float scale = __expf(m - mn);
            s *= scale;
            acc.x *= scale; acc.y *= scale; acc.z *= scale; acc.w *= scale;
            m = mn;
        }
        float w0 = __expf(p0 - m);
        float w1 = __expf(p1 - m);
        s += w0 + w1;
        acc.x += w0 * a0.x + w1 * a1.x;
        acc.y += w0 * a0.y + w1 * a1.y;
        acc.z += w0 * a0.z + w1 * a1.z;
        acc.w += w0 * a0.w + w1 * a1.w;
    }
    if (i < deg) {
        int s0 = src_sorted[start + i];
        float4 a0 = load_bf4(&xl[(size_t)s0 * DIM + lane * 4]);
        float p0 = edge_partial(a0, xr4, att4);
        #pragma unroll
        for (int o = 16; o; o >>= 1) p0 += __shfl_xor(p0, o, 32);
        if (p0 > m) {
            float scale = __expf(m - p0);
            s *= scale;
            acc.x *= scale; acc.y *= scale; acc.z *= scale; acc.w *= scale;
            m = p0;
        }
        float w0 = __expf(p0 - m);
        s += w0;
        acc.x += w0 * a0.x; acc.y += w0 * a0.y;
        acc.z += w0 * a0.z; acc.w += w0 * a0.w;
    }

    const float inv = 1.f / (s + 1e-16f);      // deg==0 -> acc==0 -> out = bias
    const float4 b4 = *reinterpret_cast<const float4*>(&bias[lane * 4]);
    float4 o4;
    o4.x = acc.x * inv + b4.x;
    o4.y = acc.y * inv + b4.y;
    o4.z = acc.z * inv + b4.z;
    o4.w = acc.w * inv + b4.w;
    *reinterpret_cast<float4*>(&out[(size_t)gl * DIM + lane * 4]) = o4;
}

// ---------------------------------------------------------------------------
// Host-side driver
// ---------------------------------------------------------------------------
extern "C" void kernel_launch(void* const* d_in, const int* in_sizes, int n_in,
                              void* d_out, int out_size, void* d_ws, size_t ws_size,
                              hipStream_t stream)
{
    const float* x_user   = (const float*)d_in[0];
    const float* x_item   = (const float*)d_in[1];
    const int*   edge_u2i = (const int*)d_in[2];
    const int*   edge_i2u = (const int*)d_in[3];
    const float* W1_user  = (const float*)d_in[4];
    const float* b1_user  = (const float*)d_in[5];
    const float* W2_user  = (const float*)d_in[6];
    const float* b2_user  = (const float*)d_in[7];
    const float* W1_item  = (const float*)d_in[8];
    const float* b1_item  = (const float*)d_in[9];
    const float* W2_item  = (const float*)d_in[10];
    const float* b2_item  = (const float*)d_in[11];
    const float* Wl_u2i   = (const float*)d_in[12];
    const float* bl_u2i   = (const float*)d_in[13];
    const float* Wr_u2i   = (const float*)d_in[14];
    const float* br_u2i   = (const float*)d_in[15];
    const float* att_u2i  = (const float*)d_in[16];
    const float* bias_u2i = (const float*)d_in[17];
    const float* Wl_i2u   = (const float*)d_in[18];
    const float* bl_i2u   = (const float*)d_in[19];
    const float* Wr_i2u   = (const float*)d_in[20];
    const float* br_i2u   = (const float*)d_in[21];
    const float* att_i2u  = (const float*)d_in[22];
    const float* bias_i2u = (const float*)d_in[23];

    const int E1 = in_sizes[2] / 2;
    const int E2 = in_sizes[3] / 2;

    const size_t NF = (size_t)N_NODES * DIM;
    ushort* XLu = (ushort*)d_ws;        // user as src (u2i)
    ushort* XRu = XLu + NF;             // user as dst (i2u)
    ushort* XLi = XRu + NF;             // item as src (i2u)
    ushort* XRi = XLi + NF;             // item as dst (u2i)
    ushort* blobU = XRi + NF;
    ushort* blobI = blobU + BLOB;
    int* counts2    = (int*)(blobI + BLOB);       // [2N]
    int* cursor2    = counts2 + 2 * N_NODES;      // [2N] (contiguous with counts2)
    int* offsets2   = cursor2 + 2 * N_NODES;      // [2N]
    int* bsums      = offsets2 + 2 * N_NODES;     // [1024]
    int* src_sorted = bsums + 1024;               // [E1+E2]

    float* out_user = (float*)d_out;
    float* out_item = out_user + NF;

    dim3 blk(256);

    // weight prep (fragment-ordered bf16 blobs)
    prep_weights<<<(BLOB + 255) / 256, blk, 0, stream>>>(
        W1_user, W2_user, Wl_u2i, Wr_i2u, blobU);
    prep_weights<<<(BLOB + 255) / 256, blk, 0, stream>>>(
        W1_item, W2_item, Wl_i2u, Wr_u2i, blobI);

    // CSR build
    hipMemsetAsync(counts2, 0, 4 * N_NODES * sizeof(int), stream);  // counts2+cursor2
    const int nthr = ((E1 + 7) / 8) + ((E2 + 7) / 8);
    count_both<<<(nthr + 255) / 256, blk, 0, stream>>>(edge_u2i, E1, edge_i2u, E2, counts2);
    const int n2 = 2 * N_NODES;
    const int nb = (n2 + 255) / 256;    // 391
    scan_partial<<<nb, blk, 0, stream>>>(counts2, bsums, n2);
    scan_bsums<<<1, 1024, 0, stream>>>(bsums, nb);
    scan_final<<<nb, blk, 0, stream>>>(counts2, bsums, offsets2, n2);
    fill_both<<<(nthr + 255) / 256, blk, 0, stream>>>(
        edge_u2i, E1, edge_i2u, E2, offsets2, cursor2, src_sorted);

    // fused dense chain, both node types in one dispatch
    const int gnt = (N_NODES + 127) / 128;   // 391
    node_transform<<<2 * gnt, dim3(512), 0, stream>>>(
        x_user, blobU, b1_user, b2_user, bl_u2i, br_i2u, XLu, XRu,
        x_item, blobI, b1_item, b2_item, bl_i2u, br_u2i, XLi, XRi,
        gnt, N_NODES);

    // aggregation, both relations in one dispatch
    const int ng = (2 * N_NODES * 32 + 255) / 256;
    // A (g<N): u2i, dst=item -> out_item ; xl=XLu, xr=XRi
    // B (g>=N): i2u, dst=user -> out_user ; xl=XLi, xr=XRu
    gat_both<<<ng, blk, 0, stream>>>(XLu, XRi, att_u2i, bias_u2i, out_item,
                                     XLi, XRu, att_i2u, bias_i2u, out_user,
                                     offsets2, counts2, src_sorted);
}